// Round 1
// 447.552 us; speedup vs baseline: 1.0117x; 1.0117x over previous
//
#include <hip/hip_runtime.h>
#include <math.h>

#define T_LEN    16000
#define T_LEN4   4000          // float4 count per row
#define THREADS  256
#define CHUNK    17            // odd -> stride-17 LDS access, conflict-free
#define TILE     (THREADS * CHUNK)   // 4352 floats = 17408 B
#define TILE4    (TILE / 4)          // 1088 float4
#define NT       4             // 4 * 4352 = 17408 >= 16000
#define EPS_F    1e-6f

// Double-buffered LDS: 2*17408 B = 34.8 KB/block. Occupancy is VGPR-capped at
// 4 blocks/CU (launch_bounds 4 waves/EU, VGPR<=128), LDS allows 4 -> no loss.
__launch_bounds__(THREADS, 4)
__global__ void pcen_kernel(const float* __restrict__ x,
                            const float* __restrict__ alpha,
                            const float* __restrict__ delta,
                            const float* __restrict__ root,
                            const float* __restrict__ ema_w,
                            float* __restrict__ out, int C) {
    __shared__ __align__(16) float buf[2][TILE];
    __shared__ float swA[4], swB[4];

    const int row  = blockIdx.x;
    const int c    = row % C;
    const int tid  = threadIdx.x;
    const int lane = tid & 63;
    const int wave = tid >> 6;

    const float s   = fminf(fmaxf(ema_w[c], 0.0f), 1.0f);
    const float q   = 1.0f - s;
    const float a_c = fminf(alpha[c], 1.0f);
    const float r   = 1.0f / fmaxf(root[c], 1.0f);
    const float d   = delta[c];
    const float dr  = powf(d, r);
    const float q17 = powf(q, (float)CHUNK);   // per-thread composed A (uniform case)
    const bool  sqrt_path = (r == 0.5f);       // root=2 -> (v+d)^r is a sqrt

    const float4* x4 = (const float4*)(x   + (size_t)row * T_LEN);
    float4*       o4 = (float4*)      (out + (size_t)row * T_LEN);

    const int lbase = tid * CHUNK;
    float e_carry = 0.0f;

    // staged-tile registers (5 float4 per thread); g4 only live for tid<64
    float4 g0, g1, g2, g3, g4 = make_float4(1.f, 1.f, 1.f, 1.f);

    auto load_tile = [&](int t) {
        const int b = t * TILE4;
        g0 = (b + tid        < T_LEN4) ? x4[b + tid       ] : make_float4(1.f,1.f,1.f,1.f);
        g1 = (b + tid +  256 < T_LEN4) ? x4[b + tid +  256] : make_float4(1.f,1.f,1.f,1.f);
        g2 = (b + tid +  512 < T_LEN4) ? x4[b + tid +  512] : make_float4(1.f,1.f,1.f,1.f);
        g3 = (b + tid +  768 < T_LEN4) ? x4[b + tid +  768] : make_float4(1.f,1.f,1.f,1.f);
        if (tid < TILE4 - 1024)   // 64 float4 tail, wave 0 only
            g4 = (b + tid + 1024 < T_LEN4) ? x4[b + tid + 1024] : make_float4(1.f,1.f,1.f,1.f);
    };

    load_tile(0);   // prologue: tile-0 loads in flight

    for (int t = 0; t < NT; ++t) {
        float*  cb  = &buf[t & 1][0];
        float4* cb4 = (float4*)cb;

        // ---- ds_write staged regs -> LDS (implicit vmcnt wait on g*) ----
        cb4[tid]       = g0;
        cb4[tid + 256] = g1;
        cb4[tid + 512] = g2;
        cb4[tid + 768] = g3;
        if (tid < TILE4 - 1024) cb4[tid + 1024] = g4;
        __syncthreads();                                     // (1) tile visible

        // ---- prefetch next tile NOW; latency hides under pass1+scan+pass2 ----
        if (t + 1 < NT) load_tile(t + 1);

        // ---- pass 1: chunk -> registers, compose (A,b) over 17 elements ----
        float xv[CHUNK];
        #pragma unroll
        for (int j = 0; j < CHUNK; ++j) xv[j] = cb[lbase + j];

        const bool ft = (t == 0) && (tid == 0);  // owns the very first element
        float la = ft ? 0.0f   : q17;            // A = 0*q^16 or q^17
        float lb = ft ? xv[0]  : s * xv[0];
        #pragma unroll
        for (int j = 1; j < CHUNK; ++j) lb = fmaf(q, lb, s * xv[j]);

        // ---- wave-level inclusive scan (Hillis-Steele, 64 lanes) ----
        #pragma unroll
        for (int off = 1; off < 64; off <<= 1) {
            float ua = __shfl_up(la, off);
            float ub = __shfl_up(lb, off);
            if (lane >= off) { lb = fmaf(la, ub, lb); la *= ua; }
        }
        if (lane == 63) { swA[wave] = la; swB[wave] = lb; }
        __syncthreads();                                     // (2) partials visible

        // ---- wave-exclusive prefix pair ----
        float pa = 1.0f, pb = 0.0f;
        #pragma unroll
        for (int w = 0; w < 3; ++w)
            if (w < wave) { pb = fmaf(swA[w], pb, swB[w]); pa *= swA[w]; }

        // ---- thread-exclusive prefix within wave ----
        float ea = __shfl_up(la, 1);
        float eb = __shfl_up(lb, 1);
        float a_ex, b_ex;
        if (lane == 0) { a_ex = pa;      b_ex = pb; }
        else           { a_ex = pa * ea; b_ex = fmaf(ea, pb, eb); }
        float e = fmaf(a_ex, e_carry, b_ex);   // EMA state entering this chunk

        // ---- tile-total -> carry for next tile (uniform across threads) ----
        float ta = 1.0f, tb = 0.0f;
        #pragma unroll
        for (int w = 0; w < 4; ++w) { tb = fmaf(swA[w], tb, swB[w]); ta *= swA[w]; }
        e_carry = fmaf(ta, e_carry, tb);

        // ---- pass 2: EMA recurrence + pointwise, all from registers ----
        // v = x * (eps+e)^-alpha  (1 log + 1 exp; the old log2(x) trans is gone)
        // (v+d)^r - d^r : sqrt when r==0.5 (this input), generic exp2/log2 else
        if (t * TILE + lbase < T_LEN) {          // skip all-padding tail threads
            if (sqrt_path) {
                #pragma unroll
                for (int j = 0; j < CHUNK; ++j) {
                    float xvj = xv[j];
                    e = (ft && j == 0) ? xvj : fmaf(q, e, s * xvj);
                    float lge = log2f(EPS_F + e);
                    float v   = xvj * exp2f(-a_c * lge);
                    cb[lbase + j] = sqrtf(v + d) - dr;
                }
            } else {
                #pragma unroll
                for (int j = 0; j < CHUNK; ++j) {
                    float xvj = xv[j];
                    e = (ft && j == 0) ? xvj : fmaf(q, e, s * xvj);
                    float lge = log2f(EPS_F + e);
                    float v   = xvj * exp2f(-a_c * lge);
                    cb[lbase + j] = exp2f(r * log2f(v + d)) - dr;
                }
            }
        }
        __syncthreads();                                     // (3) outputs visible

        // ---- store: LDS -> global, coalesced float4 ----
        // No trailing barrier: next iter writes the OTHER buffer; the implicit
        // waitcnt before barrier (1) of iter t+1 drains these ds_reads, and the
        // re-use of this buffer (iter t+2) is 3 barriers away.
        {
            const int b = t * TILE4;
            if (b + tid        < T_LEN4) o4[b + tid       ] = cb4[tid];
            if (b + tid +  256 < T_LEN4) o4[b + tid +  256] = cb4[tid + 256];
            if (b + tid +  512 < T_LEN4) o4[b + tid +  512] = cb4[tid + 512];
            if (b + tid +  768 < T_LEN4) o4[b + tid +  768] = cb4[tid + 768];
            if (tid < TILE4 - 1024 && b + tid + 1024 < T_LEN4)
                o4[b + tid + 1024] = cb4[tid + 1024];
        }
    }
}

extern "C" void kernel_launch(void* const* d_in, const int* in_sizes, int n_in,
                              void* d_out, int out_size, void* d_ws, size_t ws_size,
                              hipStream_t stream) {
    const float* x     = (const float*)d_in[0];
    const float* alpha = (const float*)d_in[1];
    const float* delta = (const float*)d_in[2];
    const float* root  = (const float*)d_in[3];
    const float* ema_w = (const float*)d_in[4];
    float* out = (float*)d_out;

    const int C    = in_sizes[1];               // 128
    const int rows = in_sizes[0] / T_LEN;       // B*C = 4096

    pcen_kernel<<<rows, THREADS, 0, stream>>>(x, alpha, delta, root, ema_w, out, C);
}